// Round 12
// baseline (450.856 us; speedup 1.0000x reference)
//
#include <hip/hip_runtime.h>
#include <stdint.h>

// ---- problem constants ----
#define NPATCH 3136      // 64 images * 49 patches
#define MPAD   3328      // 26 * 128 (= 208 * 16)
#define NBANK  100000
#define NBPAD  100096    // 6256 * 16
#define DIM    768
#define BM 128
#define BN 128
#define BK 64               // K-tile
#define KTILES (DIM / BK)   // 12
#define MT 26               // MPAD / BM
#define NT 782              // NBPAD / BN
#define NRG    (MPAD / 16)   // 208 A row-groups
#define NBRG   (NBPAD / 16)  // 6256 B row-groups
#define NCHUNK (KTILES * NRG * 64)   // 159744 16B chunks in Af

typedef __attribute__((ext_vector_type(4))) float f32x4;
typedef __attribute__((ext_vector_type(4))) int   i32x4;

// monotonic float<->uint mapping for atomicMax on floats (incl. negatives)
__device__ __forceinline__ unsigned fkey(float f) {
    unsigned u = __float_as_uint(f);
    return (u & 0x80000000u) ? ~u : (u | 0x80000000u);
}
__device__ __forceinline__ float funkey(unsigned u) {
    return __uint_as_float((u & 0x80000000u) ? (u ^ 0x80000000u) : ~u);
}

// ---- kernel 0: zero the per-patch max-key buffer ----
__global__ void k_init(unsigned* __restrict__ keys) {
    int i = blockIdx.x * 256 + threadIdx.x;
    if (i < MPAD) keys[i] = 0u;
}

// ---- shared: quantize one 768-float row to int8 with scale sa = vmax/(127*(||a||+eps))
// dst may be global or LDS (generic address space).
__device__ __forceinline__ void quant_row(const float* __restrict__ src,
                                          signed char* __restrict__ dst,
                                          float* __restrict__ sa_p, int lane) {
    f32x4 v[3];
    float ss = 0.f, vm = 0.f;
#pragma unroll
    for (int i = 0; i < 3; i++) {
        v[i] = ((const f32x4*)src)[lane + 64 * i];
#pragma unroll
        for (int c = 0; c < 4; c++) {
            ss += v[i][c] * v[i][c];
            vm = fmaxf(vm, fabsf(v[i][c]));
        }
    }
#pragma unroll
    for (int d = 1; d < 64; d <<= 1) {
        ss += __shfl_xor(ss, d);
        vm = fmaxf(vm, __shfl_xor(vm, d));
    }
    float k = (vm > 0.f) ? 127.0f / vm : 0.f;
#pragma unroll
    for (int i = 0; i < 3; i++) {
        char4 o;
        o.x = (signed char)__float2int_rn(v[i][0] * k);
        o.y = (signed char)__float2int_rn(v[i][1] * k);
        o.z = (signed char)__float2int_rn(v[i][2] * k);
        o.w = (signed char)__float2int_rn(v[i][3] * k);
        ((char4*)dst)[lane + 64 * i] = o;
    }
    if (lane == 0) *sa_p = vm / (127.0f * (sqrtf(ss) + 1e-12f));
}

__device__ __forceinline__ void zero_row(signed char* __restrict__ dst,
                                         float* __restrict__ sa_p, int lane) {
    char4 z; z.x = z.y = z.z = z.w = 0;
#pragma unroll
    for (int i = 0; i < 3; i++) ((char4*)dst)[lane + 64 * i] = z;
    if (lane == 0) *sa_p = 0.f;
}

// ---- kernel 1: patches (drop CLS) -> int8 Aq[MPAD][DIM] + sa[MPAD] ----
__global__ void k_q8a(const float* __restrict__ tokens, signed char* __restrict__ A,
                      float* __restrict__ sa) {
    int wv = threadIdx.x >> 6, lane = threadIdx.x & 63;
    int r = blockIdx.x * 4 + wv;
    if (r >= MPAD) return;
    signed char* dst = A + (size_t)r * DIM;
    if (r >= NPATCH) { zero_row(dst, sa + r, lane); return; }
    int b = r / 49, j = r % 49;
    const float* src = tokens + (size_t)(b * 50 + 1 + j) * DIM;  // skip CLS
    quant_row(src, dst, sa + r, lane);
}

// ---- kernel 1b: repack Aq row-major -> Af fragment-major (R9-proven).
// Af chunk d = ((kt*NRG + rg)*64 + khi*16 + lr) holds Aq[rg*16+lr][kt*64+khi*16 .. +16).
__global__ void k_rep(const signed char* __restrict__ Aq, signed char* __restrict__ Af) {
    int d = blockIdx.x * 256 + threadIdx.x;
    if (d >= NCHUNK) return;
    int l6 = d & 63;
    int rg = (d >> 6) % NRG;
    int kt = d / (NRG * 64);
    int row = rg * 16 + (l6 & 15);
    int kc  = kt * 64 + (l6 >> 4) * 16;
    *(i32x4*)(Af + (size_t)d * 16) = *(const i32x4*)(Aq + (size_t)row * DIM + kc);
}

// ---- kernel 2: bank -> int8 fragment-major Bf + sb, fused quant+transpose.
// One block per 16-row group: quant rows into LDS (padded stride), then write out
// 12 kt-chunks of 1 KB each, fully coalesced. Bf mirrors Af with NBRG groups.
__global__ void __launch_bounds__(256) k_q8b(const float* __restrict__ mb,
                                             signed char* __restrict__ Bf,
                                             float* __restrict__ sb) {
    __shared__ __align__(16) signed char sm[16][784];   // 784 = 768+16 (bank-spread pad)
    int rg = blockIdx.x;                                 // 0..NBRG-1
    int wv = threadIdx.x >> 6, lane = threadIdx.x & 63;
#pragma unroll
    for (int j = 0; j < 4; j++) {
        int ri = wv * 4 + j;
        int row = rg * 16 + ri;
        if (row < NBANK) quant_row(mb + (size_t)row * DIM, &sm[ri][0], sb + row, lane);
        else             zero_row(&sm[ri][0], sb + row, lane);
    }
    __syncthreads();
    int t = threadIdx.x;
#pragma unroll
    for (int i = 0; i < 3; i++) {
        int idx = i * 256 + t;          // 0..767 = kt(12) * 64 lane-chunks
        int kt = idx >> 6, l6 = idx & 63;
        i32x4 v = *(const i32x4*)(&sm[l6 & 15][kt * 64 + (l6 >> 4) * 16]);
        *(i32x4*)(Bf + (((size_t)kt * NBRG + rg) * 64 + l6) * 16) = v;
    }
}

// ---- kernel 3: int8 MFMA GEMM (16x16x64), 128x128 tile, 4 waves of 64x64.
// NO LDS, NO barriers. Operands fragment-major in global; SGPR-based addressing:
// wave-uniform base hoisted via readfirstlane (HK technique), per-lane voffset
// fixed in one VGPR, fragment selects via 13-bit imm offsets, K-advance via
// uniform pointer increment (SALU). In-loop VALU ~ 0 -> MFMA issue unblocked.
__global__ void __launch_bounds__(256, 3) k_gemm(const signed char* __restrict__ Af,
                                                 const signed char* __restrict__ Bf,
                                                 const float* __restrict__ sb,
                                                 unsigned* __restrict__ keys) {
    // T1: bijective XCD swizzle (m204; nwg=20332)
    const int nwg = MT * NT;
    const int q = nwg >> 3, r8 = nwg & 7;
    const int xcd = blockIdx.x & 7, loc = blockIdx.x >> 3;
    const int wg = (xcd < r8 ? xcd * (q + 1) : r8 * (q + 1) + (xcd - r8) * q) + loc;
    const int mt = wg % MT;          // m-fastest within an XCD: 26 blocks share one B panel
    const int nt = wg / MT;

    const int t = threadIdx.x;
    const int lane = t & 63, wv = t >> 6;
    const int lr = lane & 15;
    const int khi = lane >> 4;         // 0..3 -> 16 B k-chunk of the 64-elem k

    const int wm = (wv >> 1) * 64;
    const int wn = (wv & 1) * 64;

    const int rg0 = mt * (BM / 16) + (wm >> 4);
    const int cg0 = nt * (BN / 16) + (wn >> 4);

    // wave-uniform base offsets -> SGPR (readfirstlane); per-lane part -> one VGPR
    const unsigned aoff = __builtin_amdgcn_readfirstlane((unsigned)(rg0 << 10));
    const unsigned boff = __builtin_amdgcn_readfirstlane((unsigned)(cg0 << 10));
    const signed char* pa = Af + aoff;         // uniform pointer
    const signed char* pb = Bf + boff;         // uniform pointer
    const int voff = (khi * 16 + lr) << 4;     // 0..1023, loop-invariant VGPR

    const size_t ASTR = (size_t)NRG << 10;     // 212992 B per K-tile
    const size_t BSTR = (size_t)NBRG << 10;    // 6406144 B per K-tile

    auto loadA = [&](i32x4* a, const signed char* p) {
#pragma unroll
        for (int mi = 0; mi < 4; mi++)
            a[mi] = *(const i32x4*)(p + voff + mi * 1024);   // imm offsets 0..3072
    };
    auto loadB = [&](i32x4* b, const signed char* p) {
#pragma unroll
        for (int ni = 0; ni < 4; ni++)
            b[ni] = *(const i32x4*)(p + voff + ni * 1024);
    };

    i32x4 acc[4][4] = {};
    i32x4 aA[4], bA[4], aB[4], bB[4];
    loadA(aA, pa); loadB(bA, pb);
#pragma unroll
    for (int tt = 0; tt < KTILES; tt++) {
        if (tt + 1 < KTILES) {                       // prefetch next tile into regs
            loadA((tt & 1) ? aA : aB, pa + ASTR);
            loadB((tt & 1) ? bA : bB, pb + BSTR);
            pa += ASTR; pb += BSTR;                  // uniform SALU advance
        }
        const i32x4* av = (tt & 1) ? aB : aA;
        const i32x4* bv = (tt & 1) ? bB : bA;
#pragma unroll
        for (int mi = 0; mi < 4; mi++)
#pragma unroll
            for (int ni = 0; ni < 4; ni++)
                acc[mi][ni] = __builtin_amdgcn_mfma_i32_16x16x64_i8(
                    av[mi], bv[ni], acc[mi][ni], 0, 0, 0);
    }

    // epilogue: m = max over this block's cols of sb[col]*dot; atomicMax per row.
    // sa[row] is a positive per-row constant -> applied in k_final (max commutes).
    const int rowbase = mt * BM + wm;
    const int colbase = nt * BN + wn;
    float sbv[4];
#pragma unroll
    for (int ni = 0; ni < 4; ni++) sbv[ni] = sb[colbase + ni * 16 + lr];
#pragma unroll
    for (int mi = 0; mi < 4; mi++) {
#pragma unroll
        for (int j = 0; j < 4; j++) {
            float m = -3.4e38f;
#pragma unroll
            for (int ni = 0; ni < 4; ni++) {
                int col = colbase + ni * 16 + lr;
                if (col < NBANK) m = fmaxf(m, sbv[ni] * (float)acc[mi][ni][j]);
            }
#pragma unroll
            for (int d = 1; d < 16; d <<= 1)   // reduce 16 lanes sharing a C-row
                m = fmaxf(m, __shfl_xor(m, d));
            if (lr == 0) {
                int row = rowbase + mi * 16 + khi * 4 + j;
                if (row < NPATCH) atomicMax(&keys[row], fkey(m));
            }
        }
    }
}

// ---- kernel 4: scores[b] = max_j sqrt(max(2 - 2*sa*keymax, 1e-12)) ----
__global__ void k_final(const unsigned* __restrict__ keys, const float* __restrict__ sa,
                        float* __restrict__ out) {
    int b = threadIdx.x;
    if (b >= 64) return;
    float best = 0.f;
    for (int j = 0; j < 49; j++) {
        int row = b * 49 + j;
        float c = sa[row] * funkey(keys[row]);
        float d2 = fmaxf(2.0f - 2.0f * c, 1e-12f);
        best = fmaxf(best, sqrtf(d2));
    }
    out[b] = best;
}

extern "C" void kernel_launch(void* const* d_in, const int* in_sizes, int n_in,
                              void* d_out, int out_size, void* d_ws, size_t ws_size,
                              hipStream_t stream) {
    const float* tokens = (const float*)d_in[0];   // [64, 50, 768] f32
    const float* mb     = (const float*)d_in[1];   // [100000, 768] f32
    float* out = (float*)d_out;                    // [64] f32

    // ws layout (16B-aligned regions):
    //   Aq i8 [MPAD*DIM] | Af i8 [NCHUNK*16] | Bf i8 [KTILES*NBRG*64*16]
    //   | sa f32[MPAD] | sb f32[NBPAD] | keys u32[MPAD]
    char* ws = (char*)d_ws;
    signed char* Aq = (signed char*)ws;
    signed char* Af = (signed char*)(ws + (size_t)MPAD * DIM);
    signed char* Bf = (signed char*)(ws + (size_t)MPAD * DIM + (size_t)NCHUNK * 16);
    float* sa       = (float*)(ws + (size_t)MPAD * DIM + (size_t)NCHUNK * 16
                                  + (size_t)KTILES * NBRG * 64 * 16);
    float* sb       = sa + MPAD;
    unsigned* keys  = (unsigned*)(sb + NBPAD);

    k_init <<<(MPAD + 255) / 256, 256, 0, stream>>>(keys);
    k_q8a  <<<MPAD / 4, 256, 0, stream>>>(tokens, Aq, sa);
    k_rep  <<<(NCHUNK + 255) / 256, 256, 0, stream>>>(Aq, Af);
    k_q8b  <<<NBRG, 256, 0, stream>>>(mb, Bf, sb);
    k_gemm <<<MT * NT, 256, 0, stream>>>(Af, Bf, sb, keys);
    k_final<<<1, 64, 0, stream>>>(keys, sa, out);
}

// Round 13
// 409.016 us; speedup vs baseline: 1.1023x; 1.1023x over previous
//
#include <hip/hip_runtime.h>
#include <stdint.h>

// ---- problem constants ----
#define NPATCH 3136      // 64 images * 49 patches
#define MPAD   3328      // 26 * 128 (= 208 * 16)
#define NBANK  100000
#define NBPAD  100096    // 6256 * 16
#define DIM    768
#define BM 128
#define BN 128
#define BK 64               // K-tile
#define KTILES (DIM / BK)   // 12
#define MT 26               // MPAD / BM
#define NT 782              // NBPAD / BN
#define NRG    (MPAD / 16)   // 208 A row-groups
#define NBRG   (NBPAD / 16)  // 6256 B row-groups
#define NCHUNK (KTILES * NRG * 64)   // 159744 16B chunks in Af

typedef __attribute__((ext_vector_type(4))) float f32x4;
typedef __attribute__((ext_vector_type(4))) int   i32x4;

// monotonic float<->uint mapping for atomicMax on floats (incl. negatives)
__device__ __forceinline__ unsigned fkey(float f) {
    unsigned u = __float_as_uint(f);
    return (u & 0x80000000u) ? ~u : (u | 0x80000000u);
}
__device__ __forceinline__ float funkey(unsigned u) {
    return __uint_as_float((u & 0x80000000u) ? (u ^ 0x80000000u) : ~u);
}

// ---- kernel 0: zero the per-patch max-key buffer ----
__global__ void k_init(unsigned* __restrict__ keys) {
    int i = blockIdx.x * 256 + threadIdx.x;
    if (i < MPAD) keys[i] = 0u;
}

// ---- shared: quantize one 768-float row to int8 with scale sa = vmax/(127*(||a||+eps))
// dst may be global or LDS (generic address space).
__device__ __forceinline__ void quant_row(const float* __restrict__ src,
                                          signed char* __restrict__ dst,
                                          float* __restrict__ sa_p, int lane) {
    f32x4 v[3];
    float ss = 0.f, vm = 0.f;
#pragma unroll
    for (int i = 0; i < 3; i++) {
        v[i] = ((const f32x4*)src)[lane + 64 * i];
#pragma unroll
        for (int c = 0; c < 4; c++) {
            ss += v[i][c] * v[i][c];
            vm = fmaxf(vm, fabsf(v[i][c]));
        }
    }
#pragma unroll
    for (int d = 1; d < 64; d <<= 1) {
        ss += __shfl_xor(ss, d);
        vm = fmaxf(vm, __shfl_xor(vm, d));
    }
    float k = (vm > 0.f) ? 127.0f / vm : 0.f;
#pragma unroll
    for (int i = 0; i < 3; i++) {
        char4 o;
        o.x = (signed char)__float2int_rn(v[i][0] * k);
        o.y = (signed char)__float2int_rn(v[i][1] * k);
        o.z = (signed char)__float2int_rn(v[i][2] * k);
        o.w = (signed char)__float2int_rn(v[i][3] * k);
        ((char4*)dst)[lane + 64 * i] = o;
    }
    if (lane == 0) *sa_p = vm / (127.0f * (sqrtf(ss) + 1e-12f));
}

__device__ __forceinline__ void zero_row(signed char* __restrict__ dst,
                                         float* __restrict__ sa_p, int lane) {
    char4 z; z.x = z.y = z.z = z.w = 0;
#pragma unroll
    for (int i = 0; i < 3; i++) ((char4*)dst)[lane + 64 * i] = z;
    if (lane == 0) *sa_p = 0.f;
}

// ---- kernel 1: patches (drop CLS) -> int8 Aq[MPAD][DIM] + sa[MPAD] ----
__global__ void k_q8a(const float* __restrict__ tokens, signed char* __restrict__ A,
                      float* __restrict__ sa) {
    int wv = threadIdx.x >> 6, lane = threadIdx.x & 63;
    int r = blockIdx.x * 4 + wv;
    if (r >= MPAD) return;
    signed char* dst = A + (size_t)r * DIM;
    if (r >= NPATCH) { zero_row(dst, sa + r, lane); return; }
    int b = r / 49, j = r % 49;
    const float* src = tokens + (size_t)(b * 50 + 1 + j) * DIM;  // skip CLS
    quant_row(src, dst, sa + r, lane);
}

// ---- kernel 1b: repack Aq row-major -> Af fragment-major (R9-proven).
// Af chunk d = ((kt*NRG + rg)*64 + khi*16 + lr) holds Aq[rg*16+lr][kt*64+khi*16 .. +16).
__global__ void k_rep(const signed char* __restrict__ Aq, signed char* __restrict__ Af) {
    int d = blockIdx.x * 256 + threadIdx.x;
    if (d >= NCHUNK) return;
    int l6 = d & 63;
    int rg = (d >> 6) % NRG;
    int kt = d / (NRG * 64);
    int row = rg * 16 + (l6 & 15);
    int kc  = kt * 64 + (l6 >> 4) * 16;
    *(i32x4*)(Af + (size_t)d * 16) = *(const i32x4*)(Aq + (size_t)row * DIM + kc);
}

// ---- kernel 2: bank -> int8 fragment-major Bf + sb, fused quant+transpose.
// One block per 16-row group: quant rows into LDS (padded stride), then write out
// 12 kt-chunks of 1 KB each, fully coalesced. Bf mirrors Af with NBRG groups.
__global__ void __launch_bounds__(256) k_q8b(const float* __restrict__ mb,
                                             signed char* __restrict__ Bf,
                                             float* __restrict__ sb) {
    __shared__ __align__(16) signed char sm[16][784];   // 784 = 768+16 (bank-spread pad)
    int rg = blockIdx.x;                                 // 0..NBRG-1
    int wv = threadIdx.x >> 6, lane = threadIdx.x & 63;
#pragma unroll
    for (int j = 0; j < 4; j++) {
        int ri = wv * 4 + j;
        int row = rg * 16 + ri;
        if (row < NBANK) quant_row(mb + (size_t)row * DIM, &sm[ri][0], sb + row, lane);
        else             zero_row(&sm[ri][0], sb + row, lane);
    }
    __syncthreads();
    int t = threadIdx.x;
#pragma unroll
    for (int i = 0; i < 3; i++) {
        int idx = i * 256 + t;          // 0..767 = kt(12) * 64 lane-chunks
        int kt = idx >> 6, l6 = idx & 63;
        i32x4 v = *(const i32x4*)(&sm[l6 & 15][kt * 64 + (l6 >> 4) * 16]);
        *(i32x4*)(Bf + (((size_t)kt * NBRG + rg) * 64 + l6) * 16) = v;
    }
}

// ---- kernel 3: int8 MFMA GEMM (16x16x64), 128x128 tile, 4 waves of 64x64.
// NO LDS, NO barriers (R11 structure, 334 us) + DEPTH-2 register prefetch:
// 3 rotating register tile-buffers; loads for tile t+2 issued while computing
// tile t -> ~2 tile-periods (>700 cyc) of latency coverage per wave, enough for
// L3-class load latency. VGPR ~180 -> 2 waves/SIMD (launch_bounds(256,2)).
__global__ void __launch_bounds__(256, 2) k_gemm(const signed char* __restrict__ Af,
                                                 const signed char* __restrict__ Bf,
                                                 const float* __restrict__ sb,
                                                 unsigned* __restrict__ keys) {
    // T1: bijective XCD swizzle (m204; nwg=20332)
    const int nwg = MT * NT;
    const int q = nwg >> 3, r8 = nwg & 7;
    const int xcd = blockIdx.x & 7, loc = blockIdx.x >> 3;
    const int wg = (xcd < r8 ? xcd * (q + 1) : r8 * (q + 1) + (xcd - r8) * q) + loc;
    const int mt = wg % MT;          // m-fastest within an XCD: 26 blocks share one B panel
    const int nt = wg / MT;

    const int t = threadIdx.x;
    const int lane = t & 63, wv = t >> 6;
    const int lr = lane & 15;
    const int khi = lane >> 4;         // 0..3 -> 16 B k-chunk of the 64-elem k

    const int wm = (wv >> 1) * 64;
    const int wn = (wv & 1) * 64;

    const int rg0 = mt * (BM / 16) + (wm >> 4);
    const int cg0 = nt * (BN / 16) + (wn >> 4);
    const signed char* Afw = Af + ((size_t)rg0 * 64 + (khi * 16 + lr)) * 16;
    const signed char* Bfw = Bf + ((size_t)cg0 * 64 + (khi * 16 + lr)) * 16;

    auto loadA = [&](i32x4* a, int kt) {
#pragma unroll
        for (int mi = 0; mi < 4; mi++)
            a[mi] = *(const i32x4*)(Afw + (((size_t)kt * NRG + mi) << 10));
    };
    auto loadB = [&](i32x4* b, int kt) {
#pragma unroll
        for (int ni = 0; ni < 4; ni++)
            b[ni] = *(const i32x4*)(Bfw + (((size_t)kt * NBRG + ni) << 10));
    };

    i32x4 acc[4][4] = {};
    i32x4 a0[4], b0[4], a1[4], b1[4], a2[4], b2[4];
    loadA(a0, 0); loadB(b0, 0);          // depth-2 prologue
    loadA(a1, 1); loadB(b1, 1);
#pragma unroll
    for (int tt = 0; tt < KTILES; tt++) {
        // static 3-way rotation (tt compile-time after unroll; rule #20 safe)
        const int s = tt % 3;
        if (tt + 2 < KTILES) {           // prefetch tile tt+2 into the free buffer
            const int sn = (tt + 2) % 3;
            loadA(sn == 0 ? a0 : (sn == 1 ? a1 : a2), tt + 2);
            loadB(sn == 0 ? b0 : (sn == 1 ? b1 : b2), tt + 2);
        }
        const i32x4* av = (s == 0) ? a0 : (s == 1 ? a1 : a2);
        const i32x4* bv = (s == 0) ? b0 : (s == 1 ? b1 : b2);
        __builtin_amdgcn_s_setprio(1);
#pragma unroll
        for (int mi = 0; mi < 4; mi++)
#pragma unroll
            for (int ni = 0; ni < 4; ni++)
                acc[mi][ni] = __builtin_amdgcn_mfma_i32_16x16x64_i8(
                    av[mi], bv[ni], acc[mi][ni], 0, 0, 0);
        __builtin_amdgcn_s_setprio(0);
    }

    // epilogue: m = max over this block's cols of sb[col]*dot; atomicMax per row.
    // sa[row] is a positive per-row constant -> applied in k_final (max commutes).
    const int rowbase = mt * BM + wm;
    const int colbase = nt * BN + wn;
    float sbv[4];
#pragma unroll
    for (int ni = 0; ni < 4; ni++) sbv[ni] = sb[colbase + ni * 16 + lr];
#pragma unroll
    for (int mi = 0; mi < 4; mi++) {
#pragma unroll
        for (int j = 0; j < 4; j++) {
            float m = -3.4e38f;
#pragma unroll
            for (int ni = 0; ni < 4; ni++) {
                int col = colbase + ni * 16 + lr;
                if (col < NBANK) m = fmaxf(m, sbv[ni] * (float)acc[mi][ni][j]);
            }
#pragma unroll
            for (int d = 1; d < 16; d <<= 1)   // reduce 16 lanes sharing a C-row
                m = fmaxf(m, __shfl_xor(m, d));
            if (lr == 0) {
                int row = rowbase + mi * 16 + khi * 4 + j;
                if (row < NPATCH) atomicMax(&keys[row], fkey(m));
            }
        }
    }
}

// ---- kernel 4: scores[b] = max_j sqrt(max(2 - 2*sa*keymax, 1e-12)) ----
__global__ void k_final(const unsigned* __restrict__ keys, const float* __restrict__ sa,
                        float* __restrict__ out) {
    int b = threadIdx.x;
    if (b >= 64) return;
    float best = 0.f;
    for (int j = 0; j < 49; j++) {
        int row = b * 49 + j;
        float c = sa[row] * funkey(keys[row]);
        float d2 = fmaxf(2.0f - 2.0f * c, 1e-12f);
        best = fmaxf(best, sqrtf(d2));
    }
    out[b] = best;
}

extern "C" void kernel_launch(void* const* d_in, const int* in_sizes, int n_in,
                              void* d_out, int out_size, void* d_ws, size_t ws_size,
                              hipStream_t stream) {
    const float* tokens = (const float*)d_in[0];   // [64, 50, 768] f32
    const float* mb     = (const float*)d_in[1];   // [100000, 768] f32
    float* out = (float*)d_out;                    // [64] f32

    // ws layout (16B-aligned regions):
    //   Aq i8 [MPAD*DIM] | Af i8 [NCHUNK*16] | Bf i8 [KTILES*NBRG*64*16]
    //   | sa f32[MPAD] | sb f32[NBPAD] | keys u32[MPAD]
    char* ws = (char*)d_ws;
    signed char* Aq = (signed char*)ws;
    signed char* Af = (signed char*)(ws + (size_t)MPAD * DIM);
    signed char* Bf = (signed char*)(ws + (size_t)MPAD * DIM + (size_t)NCHUNK * 16);
    float* sa       = (float*)(ws + (size_t)MPAD * DIM + (size_t)NCHUNK * 16
                                  + (size_t)KTILES * NBRG * 64 * 16);
    float* sb       = sa + MPAD;
    unsigned* keys  = (unsigned*)(sb + NBPAD);

    k_init <<<(MPAD + 255) / 256, 256, 0, stream>>>(keys);
    k_q8a  <<<MPAD / 4, 256, 0, stream>>>(tokens, Aq, sa);
    k_rep  <<<(NCHUNK + 255) / 256, 256, 0, stream>>>(Aq, Af);
    k_q8b  <<<NBRG, 256, 0, stream>>>(mb, Bf, sb);
    k_gemm <<<MT * NT, 256, 0, stream>>>(Af, Bf, sb, keys);
    k_final<<<1, 64, 0, stream>>>(keys, sa, out);
}

// Round 14
// 329.043 us; speedup vs baseline: 1.3702x; 1.2430x over previous
//
#include <hip/hip_runtime.h>
#include <stdint.h>

// ---- problem constants ----
#define NPATCH 3136      // 64 images * 49 patches
#define MPAD   3328      // 26 * 128 (= 208 * 16)
#define NBANK  100000
#define NBPAD  100096    // 6256 * 16 = 391 * 256
#define DIM    768
#define BM 128
#define BN 256
#define BK 64               // K-tile
#define KTILES (DIM / BK)   // 12
#define MT 26               // MPAD / BM
#define NT 391              // NBPAD / BN
#define NRG    (MPAD / 16)   // 208 A row-groups
#define NBRG   (NBPAD / 16)  // 6256 B row-groups
#define NCHUNK (KTILES * NRG * 64)   // 159744 16B chunks in Af

typedef __attribute__((ext_vector_type(4))) float f32x4;
typedef __attribute__((ext_vector_type(4))) int   i32x4;

// monotonic float<->uint mapping for atomicMax on floats (incl. negatives)
__device__ __forceinline__ unsigned fkey(float f) {
    unsigned u = __float_as_uint(f);
    return (u & 0x80000000u) ? ~u : (u | 0x80000000u);
}
__device__ __forceinline__ float funkey(unsigned u) {
    return __uint_as_float((u & 0x80000000u) ? (u ^ 0x80000000u) : ~u);
}

// ---- kernel 0: zero the per-patch max-key buffer ----
__global__ void k_init(unsigned* __restrict__ keys) {
    int i = blockIdx.x * 256 + threadIdx.x;
    if (i < MPAD) keys[i] = 0u;
}

// ---- shared: quantize one 768-float row to int8 with scale sa = vmax/(127*(||a||+eps))
// dst may be global or LDS (generic address space).
__device__ __forceinline__ void quant_row(const float* __restrict__ src,
                                          signed char* __restrict__ dst,
                                          float* __restrict__ sa_p, int lane) {
    f32x4 v[3];
    float ss = 0.f, vm = 0.f;
#pragma unroll
    for (int i = 0; i < 3; i++) {
        v[i] = ((const f32x4*)src)[lane + 64 * i];
#pragma unroll
        for (int c = 0; c < 4; c++) {
            ss += v[i][c] * v[i][c];
            vm = fmaxf(vm, fabsf(v[i][c]));
        }
    }
#pragma unroll
    for (int d = 1; d < 64; d <<= 1) {
        ss += __shfl_xor(ss, d);
        vm = fmaxf(vm, __shfl_xor(vm, d));
    }
    float k = (vm > 0.f) ? 127.0f / vm : 0.f;
#pragma unroll
    for (int i = 0; i < 3; i++) {
        char4 o;
        o.x = (signed char)__float2int_rn(v[i][0] * k);
        o.y = (signed char)__float2int_rn(v[i][1] * k);
        o.z = (signed char)__float2int_rn(v[i][2] * k);
        o.w = (signed char)__float2int_rn(v[i][3] * k);
        ((char4*)dst)[lane + 64 * i] = o;
    }
    if (lane == 0) *sa_p = vm / (127.0f * (sqrtf(ss) + 1e-12f));
}

__device__ __forceinline__ void zero_row(signed char* __restrict__ dst,
                                         float* __restrict__ sa_p, int lane) {
    char4 z; z.x = z.y = z.z = z.w = 0;
#pragma unroll
    for (int i = 0; i < 3; i++) ((char4*)dst)[lane + 64 * i] = z;
    if (lane == 0) *sa_p = 0.f;
}

// ---- kernel 1: patches (drop CLS) -> int8 Aq[MPAD][DIM] + sa[MPAD] ----
__global__ void k_q8a(const float* __restrict__ tokens, signed char* __restrict__ A,
                      float* __restrict__ sa) {
    int wv = threadIdx.x >> 6, lane = threadIdx.x & 63;
    int r = blockIdx.x * 4 + wv;
    if (r >= MPAD) return;
    signed char* dst = A + (size_t)r * DIM;
    if (r >= NPATCH) { zero_row(dst, sa + r, lane); return; }
    int b = r / 49, j = r % 49;
    const float* src = tokens + (size_t)(b * 50 + 1 + j) * DIM;  // skip CLS
    quant_row(src, dst, sa + r, lane);
}

// ---- kernel 1b: repack Aq row-major -> Af fragment-major (R9-proven).
// Af chunk d = ((kt*NRG + rg)*64 + khi*16 + lr) holds Aq[rg*16+lr][kt*64+khi*16 .. +16).
__global__ void k_rep(const signed char* __restrict__ Aq, signed char* __restrict__ Af) {
    int d = blockIdx.x * 256 + threadIdx.x;
    if (d >= NCHUNK) return;
    int l6 = d & 63;
    int rg = (d >> 6) % NRG;
    int kt = d / (NRG * 64);
    int row = rg * 16 + (l6 & 15);
    int kc  = kt * 64 + (l6 >> 4) * 16;
    *(i32x4*)(Af + (size_t)d * 16) = *(const i32x4*)(Aq + (size_t)row * DIM + kc);
}

// ---- kernel 2: bank -> int8 fragment-major Bf + sb, fused quant+transpose.
// One block per 16-row group: quant rows into LDS (padded stride), then write out
// 12 kt-chunks of 1 KB each, fully coalesced. Bf mirrors Af with NBRG groups.
__global__ void __launch_bounds__(256) k_q8b(const float* __restrict__ mb,
                                             signed char* __restrict__ Bf,
                                             float* __restrict__ sb) {
    __shared__ __align__(16) signed char sm[16][784];   // 784 = 768+16 (bank-spread pad)
    int rg = blockIdx.x;                                 // 0..NBRG-1
    int wv = threadIdx.x >> 6, lane = threadIdx.x & 63;
#pragma unroll
    for (int j = 0; j < 4; j++) {
        int ri = wv * 4 + j;
        int row = rg * 16 + ri;
        if (row < NBANK) quant_row(mb + (size_t)row * DIM, &sm[ri][0], sb + row, lane);
        else             zero_row(&sm[ri][0], sb + row, lane);
    }
    __syncthreads();
    int t = threadIdx.x;
#pragma unroll
    for (int i = 0; i < 3; i++) {
        int idx = i * 256 + t;          // 0..767 = kt(12) * 64 lane-chunks
        int kt = idx >> 6, l6 = idx & 63;
        i32x4 v = *(const i32x4*)(&sm[l6 & 15][kt * 64 + (l6 >> 4) * 16]);
        *(i32x4*)(Bf + (((size_t)kt * NBRG + rg) * 64 + l6) * 16) = v;
    }
}

// ---- kernel 3: int8 MFMA GEMM (16x16x64), NO LDS / NO barriers (R11 structure).
// Per-wave tile 64x128 (4m x 8n frags): bytes/MAC 0.031 -> 0.0229, attacking the
// measured per-CU VMEM byte-rate wall (~39 B/cyc across R11/R13). Block 128x256,
// 4 waves (2M x 2N). acc 128 + dbuf operands 96 -> ~240 VGPR, 2 waves/SIMD.
__global__ void __launch_bounds__(256, 2) k_gemm(const signed char* __restrict__ Af,
                                                 const signed char* __restrict__ Bf,
                                                 const float* __restrict__ sb,
                                                 unsigned* __restrict__ keys) {
    // T1: bijective XCD swizzle (m204; nwg=10166, nwg%8=6)
    const int nwg = MT * NT;
    const int q = nwg >> 3, r8 = nwg & 7;
    const int xcd = blockIdx.x & 7, loc = blockIdx.x >> 3;
    const int wg = (xcd < r8 ? xcd * (q + 1) : r8 * (q + 1) + (xcd - r8) * q) + loc;
    const int mt = wg % MT;          // m-fastest within an XCD: 26 blocks share one B panel
    const int nt = wg / MT;

    const int t = threadIdx.x;
    const int lane = t & 63, wv = t >> 6;
    const int lr = lane & 15;
    const int khi = lane >> 4;         // 0..3 -> 16 B k-chunk of the 64-elem k

    const int wm = (wv >> 1) * 64;     // 0 or 64
    const int wn = (wv & 1) * 128;     // 0 or 128

    const int rg0 = mt * (BM / 16) + (wm >> 4);
    const int cg0 = nt * (BN / 16) + (wn >> 4);
    const signed char* Afw = Af + ((size_t)rg0 * 64 + (khi * 16 + lr)) * 16;
    const signed char* Bfw = Bf + ((size_t)cg0 * 64 + (khi * 16 + lr)) * 16;

    auto loadA = [&](i32x4* a, int kt) {
#pragma unroll
        for (int mi = 0; mi < 4; mi++)
            a[mi] = *(const i32x4*)(Afw + (((size_t)kt * NRG + mi) << 10));
    };
    auto loadB = [&](i32x4* b, int kt) {
#pragma unroll
        for (int ni = 0; ni < 8; ni++)
            b[ni] = *(const i32x4*)(Bfw + (((size_t)kt * NBRG + ni) << 10));
    };

    i32x4 acc[4][8] = {};
    i32x4 aA[4], bA[8], aB[4], bB[8];
    loadA(aA, 0); loadB(bA, 0);
#pragma unroll
    for (int tt = 0; tt < KTILES; tt++) {
        if (tt + 1 < KTILES) {                       // depth-1 register prefetch
            loadA((tt & 1) ? aA : aB, tt + 1);
            loadB((tt & 1) ? bA : bB, tt + 1);
        }
        const i32x4* av = (tt & 1) ? aB : aA;
        const i32x4* bv = (tt & 1) ? bB : bA;
        __builtin_amdgcn_s_setprio(1);
#pragma unroll
        for (int mi = 0; mi < 4; mi++)
#pragma unroll
            for (int ni = 0; ni < 8; ni++)
                acc[mi][ni] = __builtin_amdgcn_mfma_i32_16x16x64_i8(
                    av[mi], bv[ni], acc[mi][ni], 0, 0, 0);
        __builtin_amdgcn_s_setprio(0);
    }

    // epilogue: m = max over this block's cols of sb[col]*dot; atomicMax per row.
    // sa[row] is a positive per-row constant -> applied in k_final (max commutes).
    const int rowbase = mt * BM + wm;
    const int colbase = nt * BN + wn;
    float sbv[8];
    bool cok[8];
#pragma unroll
    for (int ni = 0; ni < 8; ni++) {
        int col = colbase + ni * 16 + lr;
        cok[ni] = (col < NBANK);
        sbv[ni] = sb[col];
    }
#pragma unroll
    for (int mi = 0; mi < 4; mi++) {
#pragma unroll
        for (int j = 0; j < 4; j++) {
            float m = -3.4e38f;
#pragma unroll
            for (int ni = 0; ni < 8; ni++)
                if (cok[ni]) m = fmaxf(m, sbv[ni] * (float)acc[mi][ni][j]);
#pragma unroll
            for (int d = 1; d < 16; d <<= 1)   // reduce 16 lanes sharing a C-row
                m = fmaxf(m, __shfl_xor(m, d));
            if (lr == 0) {
                int row = rowbase + mi * 16 + khi * 4 + j;
                if (row < NPATCH) atomicMax(&keys[row], fkey(m));
            }
        }
    }
}

// ---- kernel 4: scores[b] = max_j sqrt(max(2 - 2*sa*keymax, 1e-12)) ----
__global__ void k_final(const unsigned* __restrict__ keys, const float* __restrict__ sa,
                        float* __restrict__ out) {
    int b = threadIdx.x;
    if (b >= 64) return;
    float best = 0.f;
    for (int j = 0; j < 49; j++) {
        int row = b * 49 + j;
        float c = sa[row] * funkey(keys[row]);
        float d2 = fmaxf(2.0f - 2.0f * c, 1e-12f);
        best = fmaxf(best, sqrtf(d2));
    }
    out[b] = best;
}

extern "C" void kernel_launch(void* const* d_in, const int* in_sizes, int n_in,
                              void* d_out, int out_size, void* d_ws, size_t ws_size,
                              hipStream_t stream) {
    const float* tokens = (const float*)d_in[0];   // [64, 50, 768] f32
    const float* mb     = (const float*)d_in[1];   // [100000, 768] f32
    float* out = (float*)d_out;                    // [64] f32

    // ws layout (16B-aligned regions):
    //   Aq i8 [MPAD*DIM] | Af i8 [NCHUNK*16] | Bf i8 [KTILES*NBRG*64*16]
    //   | sa f32[MPAD] | sb f32[NBPAD] | keys u32[MPAD]
    char* ws = (char*)d_ws;
    signed char* Aq = (signed char*)ws;
    signed char* Af = (signed char*)(ws + (size_t)MPAD * DIM);
    signed char* Bf = (signed char*)(ws + (size_t)MPAD * DIM + (size_t)NCHUNK * 16);
    float* sa       = (float*)(ws + (size_t)MPAD * DIM + (size_t)NCHUNK * 16
                                  + (size_t)KTILES * NBRG * 64 * 16);
    float* sb       = sa + MPAD;
    unsigned* keys  = (unsigned*)(sb + NBPAD);

    k_init <<<(MPAD + 255) / 256, 256, 0, stream>>>(keys);
    k_q8a  <<<MPAD / 4, 256, 0, stream>>>(tokens, Aq, sa);
    k_rep  <<<(NCHUNK + 255) / 256, 256, 0, stream>>>(Aq, Af);
    k_q8b  <<<NBRG, 256, 0, stream>>>(mb, Bf, sb);
    k_gemm <<<MT * NT, 256, 0, stream>>>(Af, Bf, sb, keys);
    k_final<<<1, 64, 0, stream>>>(keys, sa, out);
}